// Round 3
// baseline (6592.568 us; speedup 1.0000x reference)
//
#include <hip/hip_runtime.h>
#include <hip/hip_bf16.h>

#define NNODE 4096      // B*NS = B*NT
#define NEDGE 32768
#define EMB   128
#define ORI   1024
#define SD    20
#define KKC   25
#define CIN   256       // 2*EMB
#define CHK   5         // spline k's per chunk
#define SCH   (CHK*CIN) // 1280
#define FINK  1408      // ORI + 3*EMB
#define K0LIN 1064      // ORI + 2*SD
#define KLLIN 168       // EMB + 2*SD

// ---------------- small prep kernels ----------------

// rowsum over last axis of Xt[b][s][t]: one wave per row
__global__ __launch_bounds__(256) void k_rowsum(const float* __restrict__ Xt, float* __restrict__ rowsum){
  int row = blockIdx.x*4 + (threadIdx.x >> 6);
  int lane = threadIdx.x & 63;
  const float* p = Xt + (size_t)row*512;
  float s = 0.f;
  for (int i = lane; i < 512; i += 64) s += p[i];
  for (int off = 32; off; off >>= 1) s += __shfl_xor(s, off);
  if (lane == 0) rowsum[row] = s;
}

// colsum over s of Xt[b][s][t]: one thread per (b,t), coalesced in t
__global__ __launch_bounds__(256) void k_colsum(const float* __restrict__ Xt, float* __restrict__ colsum){
  int col = blockIdx.x*256 + threadIdx.x;     // b*512 + t
  int b = col >> 9, t = col & 511;
  const float* p = Xt + (size_t)b*512*512 + t;
  float s = 0.f;
  for (int sidx = 0; sidx < 512; ++sidx) s += p[(size_t)sidx*512];
  colsum[col] = s;
}

__global__ void k_posemb(const float* __restrict__ vals, int n, float scale, float* __restrict__ out){
  int i = blockIdx.x*blockDim.x + threadIdx.x;
  if (i >= n) return;
  float x = vals[i]*scale;
  float c = -logf(10000.f)/9.f;
  for (int j = 0; j < 10; ++j) {
    float f = expf(c*(float)j);
    out[i*20 + j]      = sinf(x*f);
    out[i*20 + 10 + j] = cosf(x*f);
  }
}

// degree-1 open B-spline basis, dim=2, K=5: 4 (idx,weight) pairs per edge
__global__ void k_basis(const float* __restrict__ ea, int* __restrict__ idx4, float* __restrict__ w4){
  int e = blockIdx.x*blockDim.x + threadIdx.x;
  if (e >= NEDGE) return;
  float p0 = ea[e*2]   * 4.0f;
  float p1 = ea[e*2+1] * 4.0f;
  float l0 = floorf(p0), l1 = floorf(p1);
  float f0 = p0 - l0, f1 = p1 - l1;
  int i0 = (int)l0, i1 = (int)l1;
  int j = 0;
  for (int s1 = 0; s1 <= 1; ++s1)
    for (int s0 = 0; s0 <= 1; ++s0) {
      int a  = min(max(i0 + s0, 0), 4);
      int bb = min(max(i1 + s1, 0), 4);
      float w = (s0 ? f0 : 1.f - f0) * (s1 ? f1 : 1.f - f1);
      idx4[e*4 + j] = a + 5*bb;
      w4[e*4 + j] = w;
      ++j;
    }
}

__global__ void k_count(const int* __restrict__ dst, int* __restrict__ cnt){
  int e = blockIdx.x*256 + threadIdx.x;
  if (e < NEDGE) atomicAdd(&cnt[dst[e]], 1);
}

__global__ void k_invdeg(const int* __restrict__ cnt, float* __restrict__ inv){
  int i = blockIdx.x*256 + threadIdx.x;
  if (i < NNODE) inv[i] = 1.f / fmaxf((float)cnt[i], 1.f);
}

// exclusive prefix sum over 4096 counts -> rowptr[4097], epos copy
__global__ __launch_bounds__(256) void k_scan(const int* __restrict__ cnt, int* __restrict__ rowptr,
                                              int* __restrict__ epos){
  __shared__ int part[256];
  int tid = threadIdx.x;
  int base = tid*16;
  int v[16]; int s = 0;
  #pragma unroll
  for (int i = 0; i < 16; ++i){ v[i] = s; s += cnt[base+i]; }
  part[tid] = s; __syncthreads();
  int total = s;
  for (int off = 1; off < 256; off <<= 1){
    int y = (tid >= off) ? part[tid-off] : 0;
    __syncthreads();
    part[tid] += y;
    __syncthreads();
  }
  int excl = part[tid] - total;
  #pragma unroll
  for (int i = 0; i < 16; ++i){ int r = excl + v[i]; rowptr[base+i] = r; epos[base+i] = r; }
  if (tid == 255) rowptr[4096] = part[255];
}

__global__ void k_fill(const int* __restrict__ dst, int* __restrict__ epos, int* __restrict__ elist){
  int e = blockIdx.x*256 + threadIdx.x;
  if (e < NEDGE){ int p = atomicAdd(&epos[dst[e]], 1); elist[p] = e; }
}

// ---------------- concat builders ----------------

__global__ __launch_bounds__(256) void k_build_cat0(const float* __restrict__ x, const float* __restrict__ num,
                                                    const float* __restrict__ temb, float* __restrict__ out){
  int r = blockIdx.x;
  for (int c = threadIdx.x; c < K0LIN; c += 256) {
    float v;
    if (c < ORI)            v = x[(size_t)r*ORI + c];
    else if (c < ORI + SD)  v = num[r*SD + (c - ORI)];
    else                    v = temb[(r >> 9)*SD + (c - ORI - SD)];
    out[(size_t)r*K0LIN + c] = v;
  }
}

__global__ __launch_bounds__(256) void k_build_catl(const float* __restrict__ prev, const float* __restrict__ num,
                                                    const float* __restrict__ temb, float* __restrict__ out){
  int r = blockIdx.x;
  for (int c = threadIdx.x; c < KLLIN; c += 256) {
    float v;
    if (c < EMB)            v = prev[(size_t)r*EMB + c];
    else if (c < EMB + SD)  v = num[r*SD + (c - EMB)];
    else                    v = temb[(r >> 9)*SD + (c - EMB - SD)];
    out[(size_t)r*KLLIN + c] = v;
  }
}

__global__ __launch_bounds__(256) void k_build_final(const float* __restrict__ x, const float* __restrict__ a0,
                                                     const float* __restrict__ a1, const float* __restrict__ a2,
                                                     float* __restrict__ out){
  int r = blockIdx.x;
  for (int c = threadIdx.x; c < FINK; c += 256) {
    float v;
    if (c < ORI) v = x[(size_t)r*ORI + c];
    else {
      int cc = c - ORI;
      int lev = cc >> 7, d = cc & 127;
      const float* src = (lev == 0) ? a0 : (lev == 1) ? a1 : a2;
      v = src[(size_t)r*EMB + d];
    }
    out[(size_t)r*FINK + c] = v;
  }
}

// ---------------- GEMM: out[4096,128] (+)= A[4096,K] @ Bw[K,128], split-K atomic ----------------

__global__ __launch_bounds__(256) void k_gemm(const float* __restrict__ A, int lda,
                                              const float* __restrict__ Bw,
                                              float* __restrict__ out, int K, int kPerSplit){
  __shared__ float As[64][33];
  __shared__ float Bs[32][128];
  const int m0 = blockIdx.x * 64;
  const int k0 = blockIdx.y * kPerSplit;
  const int k1 = min(K, k0 + kPerSplit);
  const int tid = threadIdx.x;
  const int tx = tid & 15;   // n block: tx*8
  const int ty = tid >> 4;   // m block: ty*4
  float acc[4][8];
  #pragma unroll
  for (int i = 0; i < 4; ++i)
    #pragma unroll
    for (int j = 0; j < 8; ++j) acc[i][j] = 0.f;

  for (int kc = k0; kc < k1; kc += 32) {
    #pragma unroll
    for (int i = 0; i < 8; ++i) {
      int e = i*256 + tid;
      int m = e >> 5, kk = e & 31;
      int kg = kc + kk;
      As[m][kk] = (kg < k1) ? A[(size_t)(m0+m)*lda + kg] : 0.f;
    }
    #pragma unroll
    for (int i = 0; i < 16; ++i) {
      int e = i*256 + tid;
      int kk = e >> 7, n = e & 127;
      int kg = kc + kk;
      Bs[kk][n] = (kg < k1) ? Bw[(size_t)kg*128 + n] : 0.f;
    }
    __syncthreads();
    #pragma unroll 8
    for (int kk = 0; kk < 32; ++kk) {
      float a[4], b[8];
      #pragma unroll
      for (int i = 0; i < 4; ++i) a[i] = As[ty*4+i][kk];
      #pragma unroll
      for (int j = 0; j < 8; ++j) b[j] = Bs[kk][tx*8+j];
      #pragma unroll
      for (int i = 0; i < 4; ++i)
        #pragma unroll
        for (int j = 0; j < 8; ++j) acc[i][j] += a[i]*b[j];
    }
    __syncthreads();
  }
  #pragma unroll
  for (int i = 0; i < 4; ++i) {
    float* orow = out + (size_t)(m0 + ty*4 + i)*128 + tx*8;
    #pragma unroll
    for (int j = 0; j < 8; ++j) atomicAdd(&orow[j], acc[i][j]);
  }
}

__global__ __launch_bounds__(256) void k_bias(float* __restrict__ out, const float* __restrict__ bias){
  int i = blockIdx.x*256 + threadIdx.x;   // over 4096*128
  out[i] += bias[i & 127];
}

__global__ __launch_bounds__(256) void k_conv_finish(const float* __restrict__ tmp, const float* __restrict__ bias,
                                                     float* __restrict__ dst){
  int i = blockIdx.x*256 + threadIdx.x;
  dst[i] = tanhf(tmp[i] + bias[i & 127]);
}

// ---------------- einsum message + cat build ----------------
// cat_out[node] = [ xin_this[node] , xin_this[node] - msg[node] ]
// transposed=0: msg = sum_t Xt[b,r,t] * other[b,t,:]   (source side)
// transposed=1: msg = sum_s Xt[b,s,r] * other[b,s,:]   (target side)
__global__ __launch_bounds__(128) void k_msgcat(const float* __restrict__ Xt, const float* __restrict__ xin_this,
                                                const float* __restrict__ xin_other, float* __restrict__ cat_out,
                                                int transposed){
  int node = blockIdx.x;
  int b = node >> 9, r = node & 511;
  int tid = threadIdx.x;
  __shared__ float xrow[512];
  if (!transposed) {
    for (int i = tid; i < 512; i += 128) xrow[i] = Xt[(size_t)node*512 + i];
  } else {
    for (int i = tid; i < 512; i += 128) xrow[i] = Xt[((size_t)b*512 + i)*512 + r];
  }
  __syncthreads();
  float acc = 0.f;
  const float* base = xin_other + (size_t)b*512*EMB;
  for (int j = 0; j < 512; ++j) acc += xrow[j] * base[(size_t)j*EMB + tid];
  float xv = xin_this[(size_t)node*EMB + tid];
  cat_out[(size_t)node*CIN + tid]       = xv;
  cat_out[(size_t)node*CIN + EMB + tid] = xv - acc;
}

// ---------------- spline gather: per node, CSR over in-edges, chunk of 5 k's in LDS ----------------
__global__ __launch_bounds__(256) void k_gather(const float* __restrict__ cat, const int* __restrict__ srcarr,
                                                const int* __restrict__ elist, const int* __restrict__ rowptr,
                                                const int* __restrict__ idx4, const float* __restrict__ w4,
                                                const float* __restrict__ inv, float* __restrict__ S, int c0){
  __shared__ float acc[SCH];
  int node = blockIdx.x, tid = threadIdx.x;
  #pragma unroll
  for (int i = tid; i < SCH; i += 256) acc[i] = 0.f;
  // each thread touches only LDS columns == tid (mod 256): no cross-thread sharing, no barriers needed
  int beg = rowptr[node], end = rowptr[node+1];
  float wi = inv[node];
  for (int p = beg; p < end; ++p) {
    int e  = elist[p];
    int k0 = idx4[e*4], k1 = idx4[e*4+1], k2 = idx4[e*4+2], k3 = idx4[e*4+3];
    bool m0 = (unsigned)(k0-c0) < CHK, m1 = (unsigned)(k1-c0) < CHK,
         m2 = (unsigned)(k2-c0) < CHK, m3 = (unsigned)(k3-c0) < CHK;
    if (m0 | m1 | m2 | m3) {
      float xv = cat[(size_t)srcarr[e]*CIN + tid];
      if (m0) acc[(k0-c0)*256 + tid] += w4[e*4]  *wi*xv;
      if (m1) acc[(k1-c0)*256 + tid] += w4[e*4+1]*wi*xv;
      if (m2) acc[(k2-c0)*256 + tid] += w4[e*4+2]*wi*xv;
      if (m3) acc[(k3-c0)*256 + tid] += w4[e*4+3]*wi*xv;
    }
  }
  #pragma unroll
  for (int i = tid; i < SCH; i += 256) S[(size_t)node*SCH + i] = acc[i];
}

// ---------------- sim + softmax ----------------
__global__ __launch_bounds__(256) void k_sim_softmax(const float* __restrict__ hs, const float* __restrict__ ht,
                                                     float* __restrict__ out){
  int row = blockIdx.x;                 // b*512 + s
  int b = row >> 9;
  int tid = threadIdx.x;
  __shared__ float hsrow[128];
  __shared__ float red[8];
  if (tid < 128) hsrow[tid] = hs[(size_t)row*EMB + tid];
  __syncthreads();
  const float* r0 = ht + ((size_t)(b*512) + tid)*EMB;
  float v0 = 0.f, v1 = 0.f;
  for (int k = 0; k < 128; ++k) v0 += hsrow[k]*r0[k];
  const float* r1 = r0 + 256*EMB;
  for (int k = 0; k < 128; ++k) v1 += hsrow[k]*r1[k];
  int wid = tid >> 6, lane = tid & 63;
  float m = fmaxf(v0, v1);
  for (int off = 32; off; off >>= 1) m = fmaxf(m, __shfl_xor(m, off));
  if (lane == 0) red[wid] = m;
  __syncthreads();
  if (tid == 0) red[4] = fmaxf(fmaxf(red[0], red[1]), fmaxf(red[2], red[3]));
  __syncthreads();
  m = red[4];
  float e0 = expf(v0 - m), e1 = expf(v1 - m);
  float s = e0 + e1;
  for (int off = 32; off; off >>= 1) s += __shfl_xor(s, off);
  if (lane == 0) red[wid] = s;
  __syncthreads();
  if (tid == 0) red[5] = red[0] + red[1] + red[2] + red[3];
  __syncthreads();
  float inv = 1.f / red[5];
  out[(size_t)row*512 + tid]       = e0*inv;
  out[(size_t)row*512 + 256 + tid] = e1*inv;
}

// ---------------- host ----------------

extern "C" void kernel_launch(void* const* d_in, const int* in_sizes, int n_in,
                              void* d_out, int out_size, void* d_ws, size_t ws_size,
                              hipStream_t stream){
  (void)in_sizes; (void)n_in; (void)out_size; (void)ws_size;
  const float* t_in      = (const float*)d_in[0];
  const float* Xt        = (const float*)d_in[1];
  const float* x_s       = (const float*)d_in[2];
  const float* x_t       = (const float*)d_in[3];
  const float* ea_s      = (const float*)d_in[4];
  const float* ea_t      = (const float*)d_in[5];
  const float* lin0_w    = (const float*)d_in[6];
  const float* lin0_b    = (const float*)d_in[7];
  const float* lin_w     = (const float*)d_in[8];
  const float* lin_b     = (const float*)d_in[9];
  const float* conv_w    = (const float*)d_in[10];
  const float* conv_root = (const float*)d_in[11];
  const float* conv_bias = (const float*)d_in[12];
  const float* final_w   = (const float*)d_in[13];
  const float* final_b   = (const float*)d_in[14];
  const int*   ei_s      = (const int*)d_in[15];
  const int*   ei_t      = (const int*)d_in[16];
  float* out = (float*)d_out;

  char* wsb = (char*)d_ws;
  size_t off = 0;
  auto alloc = [&](size_t bytes)->char*{
    char* p = wsb + off;
    off += (bytes + 255) & ~(size_t)255;
    return p;
  };
  float* f_rowsum = (float*)alloc(NNODE*4);
  float* f_colsum = (float*)alloc(NNODE*4);
  float* f_temb   = (float*)alloc(8*SD*4);
  float* f_num_s  = (float*)alloc((size_t)NNODE*SD*4);
  float* f_num_t  = (float*)alloc((size_t)NNODE*SD*4);
  int*   i_idx_s  = (int*)  alloc((size_t)NEDGE*4*4);
  float* f_w_s    = (float*)alloc((size_t)NEDGE*4*4);
  int*   i_idx_t  = (int*)  alloc((size_t)NEDGE*4*4);
  float* f_w_t    = (float*)alloc((size_t)NEDGE*4*4);
  int*   i_cnt_s  = (int*)  alloc(NNODE*4);
  int*   i_cnt_t  = (int*)  alloc(NNODE*4);
  float* f_inv_s  = (float*)alloc(NNODE*4);
  float* f_inv_t  = (float*)alloc(NNODE*4);
  int*   i_rp_s   = (int*)  alloc((NNODE+1)*4);
  int*   i_rp_t   = (int*)  alloc((NNODE+1)*4);
  int*   i_ep_s   = (int*)  alloc(NNODE*4);
  int*   i_ep_t   = (int*)  alloc(NNODE*4);
  int*   i_el_s   = (int*)  alloc(NEDGE*4);
  int*   i_el_t   = (int*)  alloc(NEDGE*4);
  float* f_xin_s  = (float*)alloc((size_t)NNODE*EMB*4);   // reused as h_s at the end
  float* f_xin_t  = (float*)alloc((size_t)NNODE*EMB*4);   // reused as h_t at the end
  float* f_cat_s  = (float*)alloc((size_t)NNODE*CIN*4);
  float* f_cat_t  = (float*)alloc((size_t)NNODE*CIN*4);
  float* f_tmp    = (float*)alloc((size_t)NNODE*EMB*4);
  float* f_xs_s[3], *f_xs_t[3];
  for (int i = 0; i < 3; ++i) f_xs_s[i] = (float*)alloc((size_t)NNODE*EMB*4);
  for (int i = 0; i < 3; ++i) f_xs_t[i] = (float*)alloc((size_t)NNODE*EMB*4);
  // big region: max(catbuf [4096,1408] = 23.1MB, S chunk [4096,1280] = 21MB) fp32
  float* f_big    = (float*)alloc((size_t)NNODE*FINK*4);
  float* f_catbuf = f_big;
  float* f_S      = f_big;
  // total ~55 MB

  const size_t XIN_B = (size_t)NNODE*EMB*4;

  // --- prep ---
  k_rowsum<<<NNODE/4, 256, 0, stream>>>(Xt, f_rowsum);
  k_colsum<<<NNODE/256, 256, 0, stream>>>(Xt, f_colsum);
  k_posemb<<<NNODE/256, 256, 0, stream>>>(f_rowsum, NNODE, 0.1f, f_num_s);
  k_posemb<<<NNODE/256, 256, 0, stream>>>(f_colsum, NNODE, 0.1f, f_num_t);
  k_posemb<<<1, 64, 0, stream>>>(t_in, 8, 1.0f, f_temb);
  k_basis<<<NEDGE/256, 256, 0, stream>>>(ea_s, i_idx_s, f_w_s);
  k_basis<<<NEDGE/256, 256, 0, stream>>>(ea_t, i_idx_t, f_w_t);
  hipMemsetAsync(i_cnt_s, 0, NNODE*4, stream);
  hipMemsetAsync(i_cnt_t, 0, NNODE*4, stream);
  k_count<<<NEDGE/256, 256, 0, stream>>>(ei_s + NEDGE, i_cnt_s);
  k_count<<<NEDGE/256, 256, 0, stream>>>(ei_t + NEDGE, i_cnt_t);
  k_invdeg<<<NNODE/256, 256, 0, stream>>>(i_cnt_s, f_inv_s);
  k_invdeg<<<NNODE/256, 256, 0, stream>>>(i_cnt_t, f_inv_t);
  k_scan<<<1, 256, 0, stream>>>(i_cnt_s, i_rp_s, i_ep_s);
  k_scan<<<1, 256, 0, stream>>>(i_cnt_t, i_rp_t, i_ep_t);
  k_fill<<<NEDGE/256, 256, 0, stream>>>(ei_s + NEDGE, i_ep_s, i_el_s);
  k_fill<<<NEDGE/256, 256, 0, stream>>>(ei_t + NEDGE, i_ep_t, i_el_t);

  auto run_conv = [&](const float* cat, const int* ei, const int* elist, const int* rowptr,
                      const int* idx4, const float* w4, const float* invdeg, int layer, float* dstbuf){
    hipMemsetAsync(f_tmp, 0, XIN_B, stream);
    for (int c = 0; c < 5; ++c) {
      k_gather<<<NNODE, 256, 0, stream>>>(cat, ei, elist, rowptr, idx4, w4, invdeg, f_S, c*CHK);
      k_gemm<<<dim3(64, 4), 256, 0, stream>>>(f_S, SCH,
          conv_w + ((size_t)layer*KKC + c*CHK)*CIN*EMB, f_tmp, SCH, 320);
    }
    k_gemm<<<dim3(64, 2), 256, 0, stream>>>(cat, CIN, conv_root + (size_t)layer*CIN*EMB, f_tmp, CIN, 128);
    k_conv_finish<<<NNODE*EMB/256, 256, 0, stream>>>(f_tmp, conv_bias + layer*EMB, dstbuf);
  };

  for (int i = 0; i < 3; ++i) {
    const float* w = (i == 0) ? lin0_w : lin_w + (size_t)(i-1)*KLLIN*EMB;
    const float* bv = (i == 0) ? lin0_b : lin_b + (i-1)*EMB;
    int K = (i == 0) ? K0LIN : KLLIN;
    int sk = (i == 0) ? 4 : 2;
    int kps = (i == 0) ? 266 : 84;

    // source side linear
    if (i == 0) k_build_cat0<<<NNODE, 256, 0, stream>>>(x_s, f_num_s, f_temb, f_catbuf);
    else        k_build_catl<<<NNODE, 256, 0, stream>>>(f_xs_s[i-1], f_num_s, f_temb, f_catbuf);
    hipMemsetAsync(f_xin_s, 0, XIN_B, stream);
    k_gemm<<<dim3(64, sk), 256, 0, stream>>>(f_catbuf, K, w, f_xin_s, K, kps);
    k_bias<<<NNODE*EMB/256, 256, 0, stream>>>(f_xin_s, bv);

    // target side linear
    if (i == 0) k_build_cat0<<<NNODE, 256, 0, stream>>>(x_t, f_num_t, f_temb, f_catbuf);
    else        k_build_catl<<<NNODE, 256, 0, stream>>>(f_xs_t[i-1], f_num_t, f_temb, f_catbuf);
    hipMemsetAsync(f_xin_t, 0, XIN_B, stream);
    k_gemm<<<dim3(64, sk), 256, 0, stream>>>(f_catbuf, K, w, f_xin_t, K, kps);
    k_bias<<<NNODE*EMB/256, 256, 0, stream>>>(f_xin_t, bv);

    // einsum messages + conv input concat
    k_msgcat<<<NNODE, 128, 0, stream>>>(Xt, f_xin_s, f_xin_t, f_cat_s, 0);
    k_msgcat<<<NNODE, 128, 0, stream>>>(Xt, f_xin_t, f_xin_s, f_cat_t, 1);

    // spline convs
    run_conv(f_cat_s, ei_s, i_el_s, i_rp_s, i_idx_s, f_w_s, f_inv_s, i, f_xs_s[i]);
    run_conv(f_cat_t, ei_t, i_el_t, i_rp_t, i_idx_t, f_w_t, f_inv_t, i, f_xs_t[i]);
  }

  // final projection (h reuses xin buffers)
  float* f_h_s = f_xin_s;
  float* f_h_t = f_xin_t;
  k_build_final<<<NNODE, 256, 0, stream>>>(x_s, f_xs_s[0], f_xs_s[1], f_xs_s[2], f_catbuf);
  hipMemsetAsync(f_h_s, 0, XIN_B, stream);
  k_gemm<<<dim3(64, 4), 256, 0, stream>>>(f_catbuf, FINK, final_w, f_h_s, FINK, 352);
  k_bias<<<NNODE*EMB/256, 256, 0, stream>>>(f_h_s, final_b);

  k_build_final<<<NNODE, 256, 0, stream>>>(x_t, f_xs_t[0], f_xs_t[1], f_xs_t[2], f_catbuf);
  hipMemsetAsync(f_h_t, 0, XIN_B, stream);
  k_gemm<<<dim3(64, 4), 256, 0, stream>>>(f_catbuf, FINK, final_w, f_h_t, FINK, 352);
  k_bias<<<NNODE*EMB/256, 256, 0, stream>>>(f_h_t, final_b);

  // similarity + softmax
  k_sim_softmax<<<NNODE, 256, 0, stream>>>(f_h_s, f_h_t, out);
}

// Round 6
// 2386.597 us; speedup vs baseline: 2.7623x; 2.7623x over previous
//
#include <hip/hip_runtime.h>
#include <hip/hip_bf16.h>

typedef __hip_bfloat16 hb;
typedef short short8 __attribute__((ext_vector_type(8)));
typedef float f32x4 __attribute__((ext_vector_type(4)));

#define NNODE 4096      // per side
#define NEDGE 32768
#define EMB   128
#define ORI   1024
#define SD    20
#define CIN   256       // 2*EMB
#define NCV   3328      // 26*128 (25 spline slots + root slot)
#define FINK  1408      // ORI + 3*EMB
#define K0LIN 1064      // ORI + 2*SD
#define KLLIN 168       // EMB + 2*SD

__device__ __forceinline__ float b2f(hb v){ return __bfloat162float(v); }
__device__ __forceinline__ hb f2b(float v){ return __float2bfloat16(v); }

// split fp32 -> (hi, lo) bf16 pair; x ≈ hi + lo with ~2^-18 relative error
__device__ __forceinline__ void split2(float x, unsigned short& hi, unsigned short& lo){
  hb h = f2b(x);
  float r = x - b2f(h);
  hb l = f2b(r);
  __builtin_memcpy(&hi, &h, 2);
  __builtin_memcpy(&lo, &l, 2);
}

// ---------------- prep kernels ----------------

__global__ __launch_bounds__(256) void k_rowsum(const float* __restrict__ Xt, float* __restrict__ rowsum){
  int row = blockIdx.x*4 + (threadIdx.x >> 6);
  int lane = threadIdx.x & 63;
  const float* p = Xt + (size_t)row*512;
  float s = 0.f;
  for (int i = lane; i < 512; i += 64) s += p[i];
  for (int off = 32; off; off >>= 1) s += __shfl_xor(s, off);
  if (lane == 0) rowsum[row] = s;
}

__global__ __launch_bounds__(256) void k_colsum(const float* __restrict__ Xt, float* __restrict__ colsum){
  int col = blockIdx.x*256 + threadIdx.x;     // b*512 + t
  int b = col >> 9, t = col & 511;
  const float* p = Xt + (size_t)b*512*512 + t;
  float s = 0.f;
  for (int sidx = 0; sidx < 512; ++sidx) s += p[(size_t)sidx*512];
  colsum[col] = s;
}

__global__ void k_posemb(const float* __restrict__ vals, int n, float scale, float* __restrict__ out){
  int i = blockIdx.x*blockDim.x + threadIdx.x;
  if (i >= n) return;
  float x = vals[i]*scale;
  float c = -logf(10000.f)/9.f;
  for (int j = 0; j < 10; ++j) {
    float f = expf(c*(float)j);
    out[i*20 + j]      = sinf(x*f);
    out[i*20 + 10 + j] = cosf(x*f);
  }
}

__global__ void k_basis(const float* __restrict__ ea, int* __restrict__ idx4, float* __restrict__ w4){
  int e = blockIdx.x*blockDim.x + threadIdx.x;
  if (e >= NEDGE) return;
  float p0 = ea[e*2]   * 4.0f;
  float p1 = ea[e*2+1] * 4.0f;
  float l0 = floorf(p0), l1 = floorf(p1);
  float f0 = p0 - l0, f1 = p1 - l1;
  int i0 = (int)l0, i1 = (int)l1;
  int j = 0;
  for (int s1 = 0; s1 <= 1; ++s1)
    for (int s0 = 0; s0 <= 1; ++s0) {
      int a  = min(max(i0 + s0, 0), 4);
      int bb = min(max(i1 + s1, 0), 4);
      float w = (s0 ? f0 : 1.f - f0) * (s1 ? f1 : 1.f - f1);
      idx4[e*4 + j] = a + 5*bb;
      w4[e*4 + j] = w;
      ++j;
    }
}

__global__ void k_count(const int* __restrict__ dst, int* __restrict__ cnt){
  int e = blockIdx.x*256 + threadIdx.x;
  if (e < NEDGE) atomicAdd(&cnt[dst[e]], 1);
}

__global__ void k_invdeg(const int* __restrict__ cnt, float* __restrict__ inv){
  int i = blockIdx.x*256 + threadIdx.x;
  if (i < NNODE) inv[i] = 1.f / fmaxf((float)cnt[i], 1.f);
}

__global__ __launch_bounds__(256) void k_scan(const int* __restrict__ cnt, int* __restrict__ rowptr,
                                              int* __restrict__ epos){
  __shared__ int part[256];
  int tid = threadIdx.x;
  int base = tid*16;
  int v[16]; int s = 0;
  #pragma unroll
  for (int i = 0; i < 16; ++i){ v[i] = s; s += cnt[base+i]; }
  part[tid] = s; __syncthreads();
  int total = s;
  for (int off = 1; off < 256; off <<= 1){
    int y = (tid >= off) ? part[tid-off] : 0;
    __syncthreads();
    part[tid] += y;
    __syncthreads();
  }
  int excl = part[tid] - total;
  #pragma unroll
  for (int i = 0; i < 16; ++i){ int r = excl + v[i]; rowptr[base+i] = r; epos[base+i] = r; }
  if (tid == 255) rowptr[4096] = part[255];
}

__global__ void k_fill(const int* __restrict__ dst, int* __restrict__ epos, int* __restrict__ elist){
  int e = blockIdx.x*256 + threadIdx.x;
  if (e < NEDGE){ int p = atomicAdd(&epos[dst[e]], 1); elist[p] = e; }
}

// Xt fp32 -> XtT fp32 (transposed within batch)
__global__ __launch_bounds__(256) void k_xtT(const float* __restrict__ Xt, float* __restrict__ XtT){
  __shared__ float tile[64][65];
  int b = blockIdx.z, s0 = blockIdx.y*64, t0 = blockIdx.x*64;
  const float* src = Xt + (size_t)b*262144;
  #pragma unroll 4
  for (int p = 0; p < 16; ++p) {
    int idx = p*256 + threadIdx.x;
    int r = idx >> 6, c = idx & 63;
    tile[r][c] = src[(size_t)(s0+r)*512 + t0 + c];
  }
  __syncthreads();
  #pragma unroll 4
  for (int p = 0; p < 16; ++p) {
    int idx = p*256 + threadIdx.x;
    int r = idx >> 6, c = idx & 63;   // r: t-local, c: s-local
    XtT[(size_t)b*262144 + (size_t)(t0+r)*512 + s0 + c] = tile[c][r];
  }
}

// weight [K][128] fp32 -> [128][K] fp32
__global__ void k_wT(const float* __restrict__ src, float* __restrict__ dst, int K){
  int i = blockIdx.x*256 + threadIdx.x;
  if (i >= K*128) return;
  int n = i & 127, k = i >> 7;
  dst[(size_t)n*K + k] = src[i];
}

// conv_w[25][256][128] + root[256][128] fp32 -> WcT[3328][256] fp32
__global__ void k_wc(const float* __restrict__ convw, const float* __restrict__ root, float* __restrict__ dst){
  int i = blockIdx.x*256 + threadIdx.x;   // over 3328*256
  int k = i & 255, n = i >> 8;
  float v;
  if (n < 3200) { int kk = n >> 7, col = n & 127; v = convw[((size_t)kk*256 + k)*128 + col]; }
  else          { int col = n & 127;              v = root[(size_t)k*128 + col]; }
  dst[(size_t)n*256 + k] = v;
}

// aux[8192][40]: [num(20) | temb(20)] per node, both sides
__global__ void k_aux(const float* __restrict__ nums, const float* __restrict__ numt,
                      const float* __restrict__ temb, float* __restrict__ aux){
  int i = blockIdx.x*256 + threadIdx.x;   // over 8192*40
  if (i >= 8192*40) return;
  int r = i / 40, c = i % 40;
  int side = r >> 12, local = r & 4095, b = (r >> 9) & 7;
  float v = (c < 20) ? (side ? numt : nums)[local*20 + c] : temb[b*20 + (c - 20)];
  aux[i] = v;
}

// ---------------- split-precision MFMA GEMM ----------------
// C[128m x 128n] = A[M x K] * B, fp32 in/out, internally split bf16 hi/lo (3 MFMAs).
// B as B^T [N][K] when bT=1, else [K][N]. grid (mTiles, nTiles, batch).
// flags: 1 = accumulate into outF; 2 = add bias[col]; 4 = msg epilogue
//        (out[r][c]=X[r][c], out[r][128+c]=X[r][c]-acc, out ld fixed 256, X ld 128)
__global__ __launch_bounds__(256) void k_mfma(
    const float* __restrict__ A, int lda, long aBatch,
    const float* __restrict__ B, int ldb, long bBatch, int bT,
    int K, int flags,
    float* __restrict__ outF, const float* __restrict__ bias,
    int ldo, int oRowOff, int oBatchRows,
    const float* __restrict__ X)
{
  __shared__ __align__(16) unsigned short Ah[4096], Al[4096], Bh[4096], Bl[4096];
  const int tid = threadIdx.x;
  const int lane = tid & 63, wave = tid >> 6;
  const int wm = (wave >> 1)*64, wn = (wave & 1)*64;
  const int l15 = lane & 15, q = lane >> 4;
  const int bx = blockIdx.x, by = blockIdx.y, bz = blockIdx.z;
  const float* Ab = A + (size_t)bz*aBatch + (size_t)bx*128*lda;
  const float* Bb = B + (size_t)bz*bBatch;
  f32x4 acc[4][4];
  #pragma unroll
  for (int i = 0; i < 4; ++i)
    #pragma unroll
    for (int j = 0; j < 4; ++j) acc[i][j] = (f32x4){0.f,0.f,0.f,0.f};

  for (int kc = 0; kc < K; kc += 32) {
    // stage A tile [128 m][32 k], split hi/lo
    #pragma unroll
    for (int i = 0; i < 4; ++i) {
      int idx = i*1024 + tid*4;
      int m = idx >> 5, kk = idx & 31;
      f32x4 v = (f32x4){0.f,0.f,0.f,0.f};
      if (kc + kk + 4 <= K) v = *(const f32x4*)(Ab + (size_t)m*lda + kc + kk);
      #pragma unroll
      for (int c = 0; c < 4; ++c) split2(v[c], Ah[m*32 + kk + c], Al[m*32 + kk + c]);
    }
    if (bT) {                            // B^T [N][K] -> Bs[n][k]
      #pragma unroll
      for (int i = 0; i < 4; ++i) {
        int idx = i*1024 + tid*4;
        int n = idx >> 5, kk = idx & 31;
        f32x4 v = (f32x4){0.f,0.f,0.f,0.f};
        if (kc + kk + 4 <= K) v = *(const f32x4*)(Bb + (size_t)(by*128 + n)*ldb + kc + kk);
        #pragma unroll
        for (int c = 0; c < 4; ++c) split2(v[c], Bh[n*32 + kk + c], Bl[n*32 + kk + c]);
      }
    } else {                             // B [K][N] -> transpose into Bs[n][k]
      #pragma unroll
      for (int i = 0; i < 4; ++i) {
        int idx = i*1024 + tid*4;
        int kk = idx >> 7, n = idx & 127;
        f32x4 v = (f32x4){0.f,0.f,0.f,0.f};
        if (kc + kk < K) v = *(const f32x4*)(Bb + (size_t)(kc + kk)*ldb + by*128 + n);
        #pragma unroll
        for (int c = 0; c < 4; ++c) split2(v[c], Bh[(n + c)*32 + kk], Bl[(n + c)*32 + kk]);
      }
    }
    __syncthreads();
    short8 ah[4], al[4], bh[4], bl[4];
    #pragma unroll
    for (int i = 0; i < 4; ++i) {
      ah[i] = *(const short8*)&Ah[(wm + i*16 + l15)*32 + q*8];
      al[i] = *(const short8*)&Al[(wm + i*16 + l15)*32 + q*8];
    }
    #pragma unroll
    for (int j = 0; j < 4; ++j) {
      bh[j] = *(const short8*)&Bh[(wn + j*16 + l15)*32 + q*8];
      bl[j] = *(const short8*)&Bl[(wn + j*16 + l15)*32 + q*8];
    }
    #pragma unroll
    for (int i = 0; i < 4; ++i)
      #pragma unroll
      for (int j = 0; j < 4; ++j) {
        acc[i][j] = __builtin_amdgcn_mfma_f32_16x16x32_bf16(ah[i], bl[j], acc[i][j], 0, 0, 0);
        acc[i][j] = __builtin_amdgcn_mfma_f32_16x16x32_bf16(al[i], bh[j], acc[i][j], 0, 0, 0);
        acc[i][j] = __builtin_amdgcn_mfma_f32_16x16x32_bf16(ah[i], bh[j], acc[i][j], 0, 0, 0);
      }
    __syncthreads();
  }

  const int rowBase = oRowOff + bz*oBatchRows + bx*128;
  #pragma unroll
  for (int i = 0; i < 4; ++i) {
    #pragma unroll
    for (int j = 0; j < 4; ++j) {
      int col = by*128 + wn + j*16 + l15;
      #pragma unroll
      for (int r = 0; r < 4; ++r) {
        int row = rowBase + wm + i*16 + q*4 + r;
        float v = acc[i][j][r];
        if (flags & 2) v += bias[col];
        if (flags & 1) v += outF[(size_t)row*ldo + col];
        if (flags & 4) {
          float xv = X[(size_t)row*128 + col];
          outF[(size_t)row*256 + col]       = xv;
          outF[(size_t)row*256 + 128 + col] = xv - v;
        } else {
          outF[(size_t)row*ldo + col] = v;
        }
      }
    }
  }
}

// ---------------- CSR spline gather + root + bias + tanh (fp32) ----------------
__global__ __launch_bounds__(128) void k_aggtanh(const float* __restrict__ Y,
    const int* __restrict__ srcarr, const int* __restrict__ elist, const int* __restrict__ rowptr,
    const int* __restrict__ idx4, const float* __restrict__ w4, const float* __restrict__ inv,
    const float* __restrict__ bias, float* __restrict__ xsout){
  int node = blockIdx.x, tid = threadIdx.x;
  float acc = Y[(size_t)node*NCV + 3200 + tid];   // root slot (self)
  float wi = inv[node];
  int beg = rowptr[node], end = rowptr[node+1];
  for (int p = beg; p < end; ++p) {
    int e = elist[p];
    int sn = srcarr[e];
    const float* yrow = Y + (size_t)sn*NCV;
    #pragma unroll
    for (int j = 0; j < 4; ++j) {
      int k = idx4[e*4+j];
      float w = w4[e*4+j]*wi;
      acc += w * yrow[k*128 + tid];
    }
  }
  xsout[(size_t)node*EMB + tid] = tanhf(acc + bias[tid]);
}

// ---------------- softmax over contiguous fp32 rows of 512 ----------------
__global__ __launch_bounds__(256) void k_softmax(const float* __restrict__ sim, float* __restrict__ out){
  int row = blockIdx.x, tid = threadIdx.x;
  __shared__ float red[8];
  float v0 = sim[(size_t)row*512 + tid];
  float v1 = sim[(size_t)row*512 + 256 + tid];
  int wid = tid >> 6, lane = tid & 63;
  float m = fmaxf(v0, v1);
  for (int off = 32; off; off >>= 1) m = fmaxf(m, __shfl_xor(m, off));
  if (lane == 0) red[wid] = m;
  __syncthreads();
  if (tid == 0) red[4] = fmaxf(fmaxf(red[0], red[1]), fmaxf(red[2], red[3]));
  __syncthreads();
  m = red[4];
  float e0 = expf(v0 - m), e1 = expf(v1 - m);
  float s = e0 + e1;
  for (int off = 32; off; off >>= 1) s += __shfl_xor(s, off);
  if (lane == 0) red[wid] = s;
  __syncthreads();
  if (tid == 0) red[5] = red[0] + red[1] + red[2] + red[3];
  __syncthreads();
  float inv = 1.f / red[5];
  out[(size_t)row*512 + tid]       = e0*inv;
  out[(size_t)row*512 + 256 + tid] = e1*inv;
}

// ---------------- host ----------------

extern "C" void kernel_launch(void* const* d_in, const int* in_sizes, int n_in,
                              void* d_out, int out_size, void* d_ws, size_t ws_size,
                              hipStream_t stream){
  (void)in_sizes; (void)n_in; (void)out_size; (void)ws_size;
  const float* t_in      = (const float*)d_in[0];
  const float* Xt        = (const float*)d_in[1];
  const float* x_s       = (const float*)d_in[2];
  const float* x_t       = (const float*)d_in[3];
  const float* ea_s      = (const float*)d_in[4];
  const float* ea_t      = (const float*)d_in[5];
  const float* lin0_w    = (const float*)d_in[6];
  const float* lin0_b    = (const float*)d_in[7];
  const float* lin_w     = (const float*)d_in[8];
  const float* lin_b     = (const float*)d_in[9];
  const float* conv_w    = (const float*)d_in[10];
  const float* conv_root = (const float*)d_in[11];
  const float* conv_bias = (const float*)d_in[12];
  const float* final_w   = (const float*)d_in[13];
  const float* final_b   = (const float*)d_in[14];
  const int*   ei_s      = (const int*)d_in[15];
  const int*   ei_t      = (const int*)d_in[16];
  float* out = (float*)d_out;

  char* wsb = (char*)d_ws;
  size_t off = 0;
  auto alloc = [&](size_t bytes)->char*{
    char* p = wsb + off;
    off += (bytes + 255) & ~(size_t)255;
    return p;
  };
  float* f_rowsum = (float*)alloc(NNODE*4);
  float* f_colsum = (float*)alloc(NNODE*4);
  float* f_temb   = (float*)alloc(8*SD*4);
  float* f_num_s  = (float*)alloc((size_t)NNODE*SD*4);
  float* f_num_t  = (float*)alloc((size_t)NNODE*SD*4);
  int*   i_idx_s  = (int*)  alloc((size_t)NEDGE*4*4);
  float* f_w_s    = (float*)alloc((size_t)NEDGE*4*4);
  int*   i_idx_t  = (int*)  alloc((size_t)NEDGE*4*4);
  float* f_w_t    = (float*)alloc((size_t)NEDGE*4*4);
  int*   i_cnt_s  = (int*)  alloc(NNODE*4);
  int*   i_cnt_t  = (int*)  alloc(NNODE*4);
  float* f_inv_s  = (float*)alloc(NNODE*4);
  float* f_inv_t  = (float*)alloc(NNODE*4);
  int*   i_rp_s   = (int*)  alloc((NNODE+1)*4);
  int*   i_rp_t   = (int*)  alloc((NNODE+1)*4);
  int*   i_ep_s   = (int*)  alloc(NNODE*4);
  int*   i_ep_t   = (int*)  alloc(NNODE*4);
  int*   i_el_s   = (int*)  alloc(NEDGE*4);
  int*   i_el_t   = (int*)  alloc(NEDGE*4);
  float* f_XtT    = (float*)alloc((size_t)8*512*512*4);      // 8.4 MB
  float* f_lin0T  = (float*)alloc((size_t)128*K0LIN*4);
  float* f_lin1T  = (float*)alloc((size_t)128*KLLIN*4);
  float* f_lin2T  = (float*)alloc((size_t)128*KLLIN*4);
  float* f_finT   = (float*)alloc((size_t)128*FINK*4);
  float* f_wcT    = (float*)alloc((size_t)3*NCV*CIN*4);      // 10.2 MB
  float* f_aux    = (float*)alloc((size_t)8192*40*4);
  float* f_xin    = (float*)alloc((size_t)2*NNODE*EMB*4);    // reused as h at the end
  float* f_cat    = (float*)alloc((size_t)2*NNODE*CIN*4);    // 8.4 MB
  float* f_xs[2][3];
  for (int s = 0; s < 2; ++s)
    for (int l = 0; l < 3; ++l) f_xs[s][l] = (float*)alloc((size_t)NNODE*EMB*4);
  float* f_Y      = (float*)alloc((size_t)NNODE*NCV*4);      // 54.5 MB; sim aliases this
  float* f_sim    = f_Y;                                      // disjoint lifetimes
  // total ~104 MB

  auto gemm = [&](const float* A, int lda, long aB, const float* B, int ldb, long bB, int bT,
                  int K, int flags, float* o, const float* bias, int ldo, int rowOff, int oBR,
                  const float* X, dim3 grid){
    k_mfma<<<grid, 256, 0, stream>>>(A, lda, aB, B, ldb, bB, bT, K, flags, o, bias, ldo, rowOff, oBR, X);
  };

  // --- prep ---
  k_xtT<<<dim3(8,8,8), 256, 0, stream>>>(Xt, f_XtT);
  k_rowsum<<<NNODE/4, 256, 0, stream>>>(Xt, f_rowsum);
  k_colsum<<<NNODE/256, 256, 0, stream>>>(Xt, f_colsum);
  k_posemb<<<NNODE/256, 256, 0, stream>>>(f_rowsum, NNODE, 0.1f, f_num_s);
  k_posemb<<<NNODE/256, 256, 0, stream>>>(f_colsum, NNODE, 0.1f, f_num_t);
  k_posemb<<<1, 64, 0, stream>>>(t_in, 8, 1.0f, f_temb);
  k_aux<<<(8192*40+255)/256, 256, 0, stream>>>(f_num_s, f_num_t, f_temb, f_aux);
  k_basis<<<NEDGE/256, 256, 0, stream>>>(ea_s, i_idx_s, f_w_s);
  k_basis<<<NEDGE/256, 256, 0, stream>>>(ea_t, i_idx_t, f_w_t);
  hipMemsetAsync(i_cnt_s, 0, NNODE*4, stream);
  hipMemsetAsync(i_cnt_t, 0, NNODE*4, stream);
  k_count<<<NEDGE/256, 256, 0, stream>>>(ei_s + NEDGE, i_cnt_s);
  k_count<<<NEDGE/256, 256, 0, stream>>>(ei_t + NEDGE, i_cnt_t);
  k_invdeg<<<NNODE/256, 256, 0, stream>>>(i_cnt_s, f_inv_s);
  k_invdeg<<<NNODE/256, 256, 0, stream>>>(i_cnt_t, f_inv_t);
  k_scan<<<1, 256, 0, stream>>>(i_cnt_s, i_rp_s, i_ep_s);
  k_scan<<<1, 256, 0, stream>>>(i_cnt_t, i_rp_t, i_ep_t);
  k_fill<<<NEDGE/256, 256, 0, stream>>>(ei_s + NEDGE, i_ep_s, i_el_s);
  k_fill<<<NEDGE/256, 256, 0, stream>>>(ei_t + NEDGE, i_ep_t, i_el_t);
  k_wT<<<(K0LIN*128)/256, 256, 0, stream>>>(lin0_w, f_lin0T, K0LIN);
  k_wT<<<(KLLIN*128)/256 + 1, 256, 0, stream>>>(lin_w, f_lin1T, KLLIN);
  k_wT<<<(KLLIN*128)/256 + 1, 256, 0, stream>>>(lin_w + (size_t)KLLIN*128, f_lin2T, KLLIN);
  k_wT<<<(FINK*128)/256, 256, 0, stream>>>(final_w, f_finT, FINK);
  for (int l = 0; l < 3; ++l)
    k_wc<<<(NCV*CIN)/256, 256, 0, stream>>>(conv_w + (size_t)l*25*CIN*128,
                                            conv_root + (size_t)l*CIN*128,
                                            f_wcT + (size_t)l*NCV*CIN);

  for (int i = 0; i < 3; ++i) {
    const float* wT = (i == 0) ? f_lin0T : (i == 1) ? f_lin1T : f_lin2T;
    const float* bv = (i == 0) ? lin0_b : lin_b + (i-1)*EMB;
    int Kfull = (i == 0) ? K0LIN : KLLIN;
    int Kx = Kfull - 40;   // 1024 or 128

    // lin: xin = [x|num|temb] @ W + b, as two split-K passes (no concat copy)
    for (int side = 0; side < 2; ++side) {
      const float* Axp = (i == 0) ? (side ? x_t : x_s) : f_xs[side][i-1];
      gemm(Axp, Kx, 0, wT, Kfull, 0, 1, Kx, 0,
           f_xin, nullptr, EMB, side*NNODE, 0, nullptr, dim3(32,1,1));
      gemm(f_aux + (size_t)side*NNODE*40, 40, 0, wT + Kx, Kfull, 0, 1, 40, 1|2,
           f_xin, bv, EMB, side*NNODE, 0, nullptr, dim3(32,1,1));
    }

    // msg (batched over b) + fused cat build: cat=[xin, xin - msg]
    gemm(Xt, 512, 262144, f_xin + (size_t)NNODE*EMB, 128, 65536, 0, 512, 4,
         f_cat, nullptr, 256, 0, 512, f_xin, dim3(4,1,8));
    gemm(f_XtT, 512, 262144, f_xin, 128, 65536, 0, 512, 4,
         f_cat, nullptr, 256, NNODE, 512, f_xin, dim3(4,1,8));

    // spline conv per side: Y = cat_side @ [W_0..W_24|root], then CSR gather + tanh
    for (int side = 0; side < 2; ++side) {
      gemm(f_cat + (size_t)side*NNODE*CIN, CIN, 0, f_wcT + (size_t)i*NCV*CIN, CIN, 0, 1, CIN, 0,
           f_Y, nullptr, NCV, 0, 0, nullptr, dim3(32,26,1));
      k_aggtanh<<<NNODE, 128, 0, stream>>>(f_Y,
          side ? ei_t : ei_s, side ? i_el_t : i_el_s, side ? i_rp_t : i_rp_s,
          side ? i_idx_t : i_idx_s, side ? f_w_t : f_w_s, side ? f_inv_t : f_inv_s,
          conv_bias + i*EMB, f_xs[side][i]);
    }
  }

  // final projection -> h (reuse f_xin), as 4 split-K passes per side (no concat copy)
  float* f_h = f_xin;
  for (int side = 0; side < 2; ++side) {
    const float* xp = side ? x_t : x_s;
    gemm(xp, ORI, 0, f_finT, FINK, 0, 1, ORI, 0,
         f_h, nullptr, EMB, side*NNODE, 0, nullptr, dim3(32,1,1));
    for (int l = 0; l < 3; ++l) {
      int fl = 1 | (l == 2 ? 2 : 0);
      gemm(f_xs[side][l], EMB, 0, f_finT + ORI + l*EMB, FINK, 0, 1, EMB, fl,
           f_h, final_b, EMB, side*NNODE, 0, nullptr, dim3(32,1,1));
    }
  }

  // sim[4096,512] = hs @ ht^T (batched over b)
  gemm(f_h, EMB, 65536, f_h + (size_t)NNODE*EMB, EMB, 65536, 1, EMB, 0,
       f_sim, nullptr, 512, 0, 512, nullptr, dim3(4,4,8));

  k_softmax<<<NNODE, 256, 0, stream>>>(f_sim, out);
}